// Round 7
// baseline (130.908 us; speedup 1.0000x reference)
//
#include <hip/hip_runtime.h>
#include <math.h>

#define L 2048
#define LMASK (L - 1)
#define LB 512            // int4-blocks per row
#define LBMASK (LB - 1)
#define NCELL (L * L)
#define H 64
#define BLK 256

#define R1_BLOCKS 256
#define R1_ITERS (NCELL / 4 / (R1_BLOCKS * BLK))   // 16

// ws layout: [0] counter (uint, memset to 0) | +128: partials[256] | +8192: table[48]

// ---------------- Kernel 1: reduce + last-block MLP table ----------------
__global__ __launch_bounds__(BLK)
void reduce_mlp_kernel(const int* __restrict__ state,
                       const float* __restrict__ W1, const float* __restrict__ b1,
                       const float* __restrict__ W2, const float* __restrict__ b2,
                       const float* __restrict__ Wa, const float* __restrict__ ba,
                       const float* __restrict__ Wc, const float* __restrict__ bc,
                       unsigned int* counter, int* partials, float* table) {
    const int t = threadIdx.x;
    const int4* s4 = (const int4*)state;

    int x = 0;
    #pragma unroll
    for (int k = 0; k < R1_ITERS; ++k) {
        int4 v = s4[blockIdx.x * (BLK * R1_ITERS) + k * BLK + t];
        x += v.x + v.y + v.z + v.w;
    }
    #pragma unroll
    for (int off = 32; off > 0; off >>= 1) x += __shfl_down(x, off, 64);

    __shared__ int ls[4];
    __shared__ int islast;
    if ((t & 63) == 0) ls[t >> 6] = x;
    __syncthreads();
    if (t == 0) {
        int s = ls[0] + ls[1] + ls[2] + ls[3];
        __hip_atomic_store(&partials[blockIdx.x], s,
                           __ATOMIC_RELEASE, __HIP_MEMORY_SCOPE_AGENT);
        unsigned int old = __hip_atomic_fetch_add(counter, 1u,
                           __ATOMIC_ACQ_REL, __HIP_MEMORY_SCOPE_AGENT);
        islast = (old == R1_BLOCKS - 1) ? 1 : 0;
    }
    __syncthreads();
    if (!islast) return;

    // ---- last block only: final sum + 12-combo MLP (runs ONCE) ----
    __shared__ float h1s[12][H + 1];   // +1 pad: kill 12-way bank conflicts
    __shared__ float h2s[12][H + 1];
    __shared__ float gc_s;

    int s = __hip_atomic_load(&partials[t], __ATOMIC_ACQUIRE, __HIP_MEMORY_SCOPE_AGENT);
    #pragma unroll
    for (int off = 32; off > 0; off >>= 1) s += __shfl_down(s, off, 64);
    if ((t & 63) == 0) ls[t >> 6] = s;
    __syncthreads();
    if (t == 0) gc_s = (float)(ls[0] + ls[1] + ls[2] + ls[3]) * (1.0f / (float)NCELL);
    __syncthreads();
    const float gc = gc_s;

    const int cb = t >> 4;          // combo 0..15 (12 active)
    const int kk = t & 15;          // 4 hidden dims each
    if (cb < 12) {
        float f0 = (float)(cb / 6), f1 = (float)(cb % 6);
        #pragma unroll
        for (int d = 0; d < 4; ++d) {
            int j = kk * 4 + d;
            float a = W1[j] * f0 + W1[H + j] * f1 + W1[2 * H + j] * gc + b1[j];
            h1s[cb][j] = fmaxf(a, 0.f);
        }
    }
    __syncthreads();
    if (cb < 12) {
        #pragma unroll
        for (int d = 0; d < 4; ++d) {
            int j = kk * 4 + d;
            float acc = b2[j];
            #pragma unroll 8
            for (int q = 0; q < H; ++q) acc += h1s[cb][q] * W2[q * H + j];
            h2s[cb][j] = fmaxf(acc, 0.f);
        }
    }
    __syncthreads();
    if (t < 12) {
        float la = ba[0], lb = ba[1], v = bc[0];
        #pragma unroll 8
        for (int q = 0; q < H; ++q) {
            la += h2s[t][q] * Wa[q * 2 + 0];
            lb += h2s[t][q] * Wa[q * 2 + 1];
            v  += h2s[t][q] * Wc[q];
        }
        float m = fmaxf(la, lb);
        float e0 = expf(la - m), e1 = expf(lb - m);
        float inv = 1.f / (e0 + e1);
        table[t * 4 + 0] = e0 * inv;
        table[t * 4 + 1] = e1 * inv;
        table[t * 4 + 2] = v;
    }
}

// ---------------- Kernel 2: stencil + lookup + store ----------------
// reward = 3*(n+s+e+w) + 2*(ne+nw+se+sw) + (nn+ss+ee+ww)   [center cancels, R=5]
// Horizontal neighbors come from lane shuffles: one row = 512 int4 = 8 waves,
// so every wave sits inside one row and lane+-1 holds the adjacent int4.
__global__ __launch_bounds__(BLK)
void cell_kernel(const int* __restrict__ state,
                 const float* __restrict__ table,
                 float* __restrict__ out) {
    __shared__ float tbl[48];
    if (threadIdx.x < 48) tbl[threadIdx.x] = table[threadIdx.x];
    __syncthreads();

    int tid  = blockIdx.x * BLK + threadIdx.x;   // 0 .. NCELL/4-1
    int lane = threadIdx.x & 63;
    int i  = tid >> 9;                 // row
    int jb = tid & LBMASK;             // int4-block in row
    int im1 = (i - 1) & LMASK, ip1 = (i + 1) & LMASK;
    int im2 = (i - 2) & LMASK, ip2 = (i + 2) & LMASK;
    int jbm1 = (jb - 1) & LBMASK, jbp1 = (jb + 1) & LBMASK;

    const int4* s4 = (const int4*)state;
    const int2* s2 = (const int2*)state;

    int4 m1 = s4[i   * LB + jb];
    int4 n1 = s4[im1 * LB + jb];
    int4 q1 = s4[ip1 * LB + jb];
    int4 uu = s4[im2 * LB + jb];
    int4 dd = s4[ip2 * LB + jb];

    int m_lz = __shfl_up(m1.z, 1, 64),  m_lw = __shfl_up(m1.w, 1, 64);
    int m_rx = __shfl_down(m1.x, 1, 64), m_ry = __shfl_down(m1.y, 1, 64);
    int n_lw = __shfl_up(n1.w, 1, 64),  n_rx = __shfl_down(n1.x, 1, 64);
    int q_lw = __shfl_up(q1.w, 1, 64),  q_rx = __shfl_down(q1.x, 1, 64);

    if (lane == 0) {
        int2 v = s2[(i * LB + jbm1) * 2 + 1];        // left int4's .z,.w
        m_lz = v.x; m_lw = v.y;
        n_lw = state[im1 * L + ((jb * 4 - 1) & LMASK)];
        q_lw = state[ip1 * L + ((jb * 4 - 1) & LMASK)];
    }
    if (lane == 63) {
        int2 v = s2[(i * LB + jbp1) * 2];            // right int4's .x,.y
        m_rx = v.x; m_ry = v.y;
        n_rx = state[im1 * L + ((jb * 4 + 4) & LMASK)];
        q_rx = state[ip1 * L + ((jb * 4 + 4) & LMASK)];
    }

    int m [8] = {m_lz, m_lw, m1.x, m1.y, m1.z, m1.w, m_rx, m_ry};
    int nr[6] = {n_lw, n1.x, n1.y, n1.z, n1.w, n_rx};
    int sr[6] = {q_lw, q1.x, q1.y, q1.z, q1.w, q_rx};
    int ur[4] = {uu.x, uu.y, uu.z, uu.w};
    int dr[4] = {dd.x, dd.y, dd.z, dd.w};

    float pr[8], vv[4], rw[4];
    #pragma unroll
    for (int u = 0; u < 4; ++u) {
        int c  = m[2 + u],  w  = m[1 + u],  e  = m[3 + u];
        int ww = m[u],      ee = m[4 + u];
        int n  = nr[1 + u], nw = nr[u], ne = nr[2 + u];
        int s  = sr[1 + u], sw = sr[u], se = sr[2 + u];
        int nn = ur[u],     ss = dr[u];

        int axis1 = n + s + e + w;
        rw[u] = (float)(3 * axis1 + 2 * (nw + ne + sw + se) + (nn + ss + ww + ee));

        int combo = c * 6 + (c + axis1);
        pr[2 * u]     = tbl[combo * 4 + 0];
        pr[2 * u + 1] = tbl[combo * 4 + 1];
        vv[u]         = tbl[combo * 4 + 2];
    }

    float4* o4 = (float4*)out;
    o4[(size_t)tid * 2]     = make_float4(pr[0], pr[1], pr[2], pr[3]);
    o4[(size_t)tid * 2 + 1] = make_float4(pr[4], pr[5], pr[6], pr[7]);
    ((float4*)(out + 2 * (size_t)NCELL))[tid] = make_float4(vv[0], vv[1], vv[2], vv[3]);
    ((float4*)(out + 3 * (size_t)NCELL))[tid] = make_float4(rw[0], rw[1], rw[2], rw[3]);
}

extern "C" void kernel_launch(void* const* d_in, const int* in_sizes, int n_in,
                              void* d_out, int out_size, void* d_ws, size_t ws_size,
                              hipStream_t stream) {
    const int*   state = (const int*)d_in[0];
    const float* W1 = (const float*)d_in[1];
    const float* b1 = (const float*)d_in[2];
    const float* W2 = (const float*)d_in[3];
    const float* b2 = (const float*)d_in[4];
    const float* Wa = (const float*)d_in[5];
    const float* ba = (const float*)d_in[6];
    const float* Wc = (const float*)d_in[7];
    const float* bc = (const float*)d_in[8];
    float* out = (float*)d_out;

    unsigned int* counter  = (unsigned int*)d_ws;
    int*          partials = (int*)((char*)d_ws + 128);
    float*        table    = (float*)((char*)d_ws + 8192);

    hipMemsetAsync(d_ws, 0, 128, stream);   // zero the arrival counter

    reduce_mlp_kernel<<<R1_BLOCKS, BLK, 0, stream>>>(state, W1, b1, W2, b2,
                                                     Wa, ba, Wc, bc,
                                                     counter, partials, table);
    cell_kernel<<<NCELL / 4 / BLK, BLK, 0, stream>>>(state, table, out);
}